// Round 5
// baseline (75.417 us; speedup 1.0000x reference)
//
#include <hip/hip_runtime.h>
#include <stdint.h>

#define NB 8
#define NI 16
#define NC 256
#define SH 512
#define NCH 168   // 128-pixel chunks per batch: 128 (L0) + 32 (L1) + 8 (L2)

typedef __bf16 bf16x8 __attribute__((ext_vector_type(8)));
typedef float f32x4 __attribute__((ext_vector_type(4)));
typedef uint32_t u32x4 __attribute__((ext_vector_type(4)));

// ws layout (bytes) — every slot written unconditionally every call: NO memset.
static const size_t OFF_SSP = 0;                                         // f32 [NB][NCH][NI][NC]
static const size_t OFF_CNT = OFF_SSP + (size_t)NB * NCH * NI * NC * 4;  // int [NB][NCH][NI]
static const size_t OFF_KEY = OFF_CNT + (size_t)NB * NCH * NI * 4;       // u64 [NB][NCH][NI]
static const size_t WS_NEED = OFF_KEY + (size_t)NB * NCH * NI * 8;       // ~22.3 MB

__device__ __forceinline__ float4 ld4(const float* p) {
    return *reinterpret_cast<const float4*>(p);
}

// ---------------------------------------------------------------------------
// Fused per-chunk kernel. Block = 256 thr = 4 waves; owns one 128-pixel chunk
// of one (b, level).
// Phase A: instance-split mask build. tid<128 -> instances 0..7, tid>=128 ->
//   8..15; each thread: 1 pixel, 8 instances (8-deep load chain, was 16).
//   sr = exact 2x2 scribble average (bilinear, integer scale, half-pixel);
//   threshold folded to s4 > 2. 8 mask bits -> u8 LDS halves, merged to u16.
//   cnt via wave ballot-popcount -> LDS atomic -> per-chunk slot. Argmax key
//   only when a whole wave sees zero foreground for an instance (dead unless
//   cnt==0 globally). key = (bits(sr)<<32) | (~pix) -> max = max sr, first idx.
// Phase B: ssum[i,c] = sum_p mask[i,p]*feat[c,p] via mfma_f32_16x16x32_bf16,
//   K = 128 chunk pixels (4 k-steps). A-frag from mask words:
//   ((word>>i)&0x10001)*0x3F80 = two bf16 {0,1}. B-frag: __bf16 casts (RNE
//   v_cvt_pk_bf16_f32). C/D (m89): row=(lane>>4)*4+reg=instance, col=lane&15.
//   Wave w = channels w*64..w*64+63. Partial [16][256] -> private chunk slot.
// ---------------------------------------------------------------------------
template<int W, int S, int P>
__device__ __forceinline__ void do_chunk(const float* __restrict__ f,
                                         const float* __restrict__ scr,
                                         float* __restrict__ ssp,
                                         int* __restrict__ cntp,
                                         unsigned long long* __restrict__ keyp,
                                         int b, int chunk, int slot, int tid,
                                         uint8_t* __restrict__ lmask8,
                                         uint16_t* __restrict__ lmask16,
                                         int* __restrict__ lcnt,
                                         unsigned long long* __restrict__ lkey) {
    // ---- phase A ----
    const int gi = tid >> 7;        // instance group: 0 -> 0..7, 1 -> 8..15
    const int p = tid & 127;        // pixel within chunk
    const int pix = chunk * 128 + p;
    const int y = pix / W;
    const int x = pix - y * W;
    const int r0 = S * y + (S / 2 - 1);
    const int c0s = S * x + (S / 2 - 1);
    const int lane = tid & 63;
    const float* sb = scr + ((size_t)b * NI + gi * 8) * (SH * SH) + (size_t)r0 * SH;
    unsigned int mword = 0;
    #pragma unroll
    for (int i = 0; i < 8; ++i) {
        const float* sp = sb + (size_t)i * (SH * SH);
        float s4;
        if constexpr (S == 4) {
            // c0s-1 = 4x -> 16B-aligned float4; cols 4x+1, 4x+2 are .y/.z
            float4 q0 = ld4(sp + (c0s - 1));
            float4 q1 = ld4(sp + SH + (c0s - 1));
            s4 = (q0.y + q0.z) + (q1.y + q1.z);
        } else {
            s4 = (sp[c0s] + sp[c0s + 1]) + (sp[SH + c0s] + sp[SH + c0s + 1]);
        }
        bool bit = s4 > 2.0f;                 // == (0.25*s4 > 0.5)
        mword |= bit ? (1u << i) : 0u;
        unsigned long long bal = __ballot(bit);
        if (lane == 0) atomicAdd(&lcnt[gi * 8 + i], (int)__popcll(bal));
        if (bal == 0ull) {                    // whole wave empty -> argmax path
            unsigned int srb = __float_as_uint(0.25f * s4);
            unsigned int mx = srb;
            #pragma unroll
            for (int off = 1; off < 64; off <<= 1) {
                unsigned int o = __shfl_xor(mx, off, 64);
                mx = (o > mx) ? o : mx;
            }
            unsigned long long win = __ballot(srb == mx);
            if (lane == 0) {
                int wl = __ffsll((unsigned long long)win) - 1;  // first = smallest pix
                unsigned int wpix = (unsigned int)(chunk * 128 + (p & ~63) + wl);
                unsigned long long key = (((unsigned long long)mx) << 32)
                                       | (unsigned long long)(0xFFFFFFFFu - wpix);
                atomicMax(&lkey[gi * 8 + i], key);
            }
        }
    }
    lmask8[gi * 128 + p] = (uint8_t)mword;
    __syncthreads();
    if (tid < 128)
        lmask16[tid] = (uint16_t)(lmask8[tid] | ((unsigned)lmask8[128 + tid] << 8));
    if (tid < NI) {
        cntp[slot * NI + tid] = lcnt[tid];
        keyp[slot * NI + tid] = lkey[tid];
    }
    __syncthreads();

    // ---- phase B ----
    const int wave = tid >> 6;
    const int kg = lane >> 4;   // k-subgroup 0..3
    const int cl = lane & 15;   // channel-within-tile (B/D) AND instance row (A)
    const int c0 = wave * 64;
    const int kb = chunk * 128;
    const uint16_t* lmp = lmask16 + kg * 8;
    const float* fp0 = f + ((size_t)b * NC + c0 + cl) * P + kb + kg * 8;
    f32x4 acc0 = {0.f, 0.f, 0.f, 0.f};
    f32x4 acc1 = {0.f, 0.f, 0.f, 0.f};
    f32x4 acc2 = {0.f, 0.f, 0.f, 0.f};
    f32x4 acc3 = {0.f, 0.f, 0.f, 0.f};
    #pragma unroll
    for (int ks = 0; ks < 4; ++ks) {
        const uint4 wA = *reinterpret_cast<const uint4*>(lmp + ks * 32);
        u32x4 au;
        au.x = ((wA.x >> cl) & 0x10001u) * 0x3F80u;
        au.y = ((wA.y >> cl) & 0x10001u) * 0x3F80u;
        au.z = ((wA.z >> cl) & 0x10001u) * 0x3F80u;
        au.w = ((wA.w >> cl) & 0x10001u) * 0x3F80u;
        const bf16x8 av = __builtin_bit_cast(bf16x8, au);
        const float* fk = fp0 + ks * 32;
        #pragma unroll
        for (int nt = 0; nt < 4; ++nt) {
            const float* fr = fk + (size_t)(nt * 16) * P;
            float4 v0 = ld4(fr);
            float4 v1 = ld4(fr + 4);
            bf16x8 bv;
            bv[0] = (__bf16)v0.x; bv[1] = (__bf16)v0.y;
            bv[2] = (__bf16)v0.z; bv[3] = (__bf16)v0.w;
            bv[4] = (__bf16)v1.x; bv[5] = (__bf16)v1.y;
            bv[6] = (__bf16)v1.z; bv[7] = (__bf16)v1.w;
            if (nt == 0) acc0 = __builtin_amdgcn_mfma_f32_16x16x32_bf16(av, bv, acc0, 0, 0, 0);
            if (nt == 1) acc1 = __builtin_amdgcn_mfma_f32_16x16x32_bf16(av, bv, acc1, 0, 0, 0);
            if (nt == 2) acc2 = __builtin_amdgcn_mfma_f32_16x16x32_bf16(av, bv, acc2, 0, 0, 0);
            if (nt == 3) acc3 = __builtin_amdgcn_mfma_f32_16x16x32_bf16(av, bv, acc3, 0, 0, 0);
        }
    }
    float* sb2 = ssp + (size_t)slot * (NI * NC);
    #pragma unroll
    for (int nt = 0; nt < 4; ++nt) {
        const f32x4 ac = (nt == 0) ? acc0 : (nt == 1) ? acc1 : (nt == 2) ? acc2 : acc3;
        const int c = c0 + nt * 16 + cl;
        #pragma unroll
        for (int r = 0; r < 4; ++r)
            sb2[(kg * 4 + r) * NC + c] = ac[r];
    }
}

__global__ __launch_bounds__(256) void fused_kernel(const float* __restrict__ f0,
                                                    const float* __restrict__ f1,
                                                    const float* __restrict__ f2,
                                                    const float* __restrict__ scr,
                                                    float* __restrict__ ssp,
                                                    int* __restrict__ cntp,
                                                    unsigned long long* __restrict__ keyp) {
    __shared__ uint8_t lmask8[256];
    __shared__ __align__(16) uint16_t lmask16[128];
    __shared__ int lcnt[NI];
    __shared__ unsigned long long lkey[NI];
    const int tid = threadIdx.x;
    const int b = blockIdx.y;
    const int bx = blockIdx.x;
    if (tid < NI) { lcnt[tid] = 0; lkey[tid] = 0ull; }
    __syncthreads();
    const int slot = b * NCH + bx;
    if (bx < 128) {
        do_chunk<128, 4, 16384>(f0, scr, ssp, cntp, keyp, b, bx, slot, tid,
                                lmask8, lmask16, lcnt, lkey);
    } else if (bx < 160) {
        do_chunk<64, 8, 4096>(f1, scr, ssp, cntp, keyp, b, bx - 128, slot, tid,
                              lmask8, lmask16, lcnt, lkey);
    } else {
        do_chunk<32, 16, 1024>(f2, scr, ssp, cntp, keyp, b, bx - 160, slot, tid,
                               lmask8, lmask16, lcnt, lkey);
    }
}

// ---------------------------------------------------------------------------
// Finalize: grid (128, 4). Block = (b,i) x 64-channel quarter. 4 j-groups sum
// the per-chunk partials in parallel, LDS reduce; cnt/key reduced via LDS
// atomics. out = mean over levels of (cnt>0 ? ssum/cnt : feat[argmax]).
// ---------------------------------------------------------------------------
__global__ __launch_bounds__(256) void final_kernel(const float* __restrict__ f0,
                                                    const float* __restrict__ f1,
                                                    const float* __restrict__ f2,
                                                    const int* __restrict__ cntp,
                                                    const unsigned long long* __restrict__ keyp,
                                                    const float* __restrict__ ssp,
                                                    float* __restrict__ out) {
    __shared__ int scnt[3];
    __shared__ unsigned long long skey[3];
    __shared__ float red[4][64];
    const int bi = blockIdx.x;       // b*NI + i
    const int cq = blockIdx.y;       // channel quarter
    const int b = bi >> 4;
    const int i = bi & 15;
    const int tid = threadIdx.x;
    const int cl = tid & 63;
    const int jg = tid >> 6;
    const int CH[3] = {128, 32, 8};
    const int O[3] = {0, 128, 160};
    if (tid < 3) { scnt[tid] = 0; skey[tid] = 0ull; }
    __syncthreads();
    if (tid < NCH) {
        int l = (tid < 128) ? 0 : (tid < 160) ? 1 : 2;
        const int slot = b * NCH + tid;    // tid == O[l] + j already
        atomicAdd(&scnt[l], cntp[slot * NI + i]);
        atomicMax(&skey[l], keyp[slot * NI + i]);
    }
    __syncthreads();
    const float* fl[3] = {f0, f1, f2};
    const int Ps[3] = {16384, 4096, 1024};
    float r = 0.f;
    #pragma unroll
    for (int l = 0; l < 3; ++l) {
        const int cn = scnt[l];          // block-uniform
        if (cn > 0) {
            float s = 0.f;
            for (int j = jg; j < CH[l]; j += 4)
                s += ssp[((size_t)(b * NCH + O[l] + j) * NI + i) * NC + cq * 64 + cl];
            red[jg][cl] = s;
            __syncthreads();
            if (jg == 0)
                r += ((red[0][cl] + red[1][cl]) + (red[2][cl] + red[3][cl])) / (float)cn;
            __syncthreads();
        } else if (jg == 0) {
            unsigned int p = 0xFFFFFFFFu - (unsigned int)(skey[l] & 0xFFFFFFFFull);
            r += fl[l][((size_t)b * NC + cq * 64 + cl) * Ps[l] + p];
        }
    }
    if (jg == 0) out[(size_t)bi * NC + cq * 64 + cl] = r * (1.f / 3.f);
}

extern "C" void kernel_launch(void* const* d_in, const int* in_sizes, int n_in,
                              void* d_out, int out_size, void* d_ws, size_t ws_size,
                              hipStream_t stream) {
    const float* f0  = (const float*)d_in[0];   // [8,256,128,128]
    const float* f1  = (const float*)d_in[1];   // [8,256,64,64]
    const float* f2  = (const float*)d_in[2];   // [8,256,32,32]
    const float* scr = (const float*)d_in[3];   // [8,16,512,512]
    float* out = (float*)d_out;                 // [8,16,256]
    char* ws = (char*)d_ws;
    if (ws_size < WS_NEED) return;  // visible failure rather than corruption

    float* ssp = (float*)(ws + OFF_SSP);
    int* cntp = (int*)(ws + OFF_CNT);
    unsigned long long* keyp = (unsigned long long*)(ws + OFF_KEY);

    // no memset: every ws slot below is written unconditionally each call
    fused_kernel<<<dim3(NCH, NB), 256, 0, stream>>>(f0, f1, f2, scr, ssp, cntp, keyp);
    final_kernel<<<dim3(NB * NI, 4), 256, 0, stream>>>(f0, f1, f2, cntp, keyp, ssp, out);
}

// Round 6
// 69.612 us; speedup vs baseline: 1.0834x; 1.0834x over previous
//
#include <hip/hip_runtime.h>
#include <stdint.h>

#define NB 8
#define NI 16
#define NC 256
#define SH 512
#define NCH 84   // 256-pixel chunks per batch: 64 (L0) + 16 (L1) + 4 (L2)

typedef __bf16 bf16x8 __attribute__((ext_vector_type(8)));
typedef float f32x4 __attribute__((ext_vector_type(4)));
typedef uint32_t u32x4 __attribute__((ext_vector_type(4)));

// ws layout (bytes) — every slot written unconditionally every call: NO memset.
static const size_t OFF_SSP = 0;                                         // f32 [NB][NCH][NI][NC]
static const size_t OFF_CNT = OFF_SSP + (size_t)NB * NCH * NI * NC * 4;  // int [NB][NCH][NI]
static const size_t OFF_KEY = OFF_CNT + (size_t)NB * NCH * NI * 4;       // u64 [NB][NCH][NI]
static const size_t WS_NEED = OFF_KEY + (size_t)NB * NCH * NI * 8;       // ~11.1 MB

__device__ __forceinline__ float4 ld4(const float* p) {
    return *reinterpret_cast<const float4*>(p);
}

// One MFMA k-step: build A-frag from mask words, pack B-frag from prefetched
// float4s (RNE v_cvt_pk_bf16_f32 via __bf16 casts), 4 n-tile MFMAs.
__device__ __forceinline__ void mfma_step(const uint16_t* __restrict__ lmp, int ks, int cl,
                                          const float4 (&buf)[4][2],
                                          f32x4& a0, f32x4& a1, f32x4& a2, f32x4& a3) {
    const uint4 wA = *reinterpret_cast<const uint4*>(lmp + ks * 32);
    u32x4 au;
    au.x = ((wA.x >> cl) & 0x10001u) * 0x3F80u;
    au.y = ((wA.y >> cl) & 0x10001u) * 0x3F80u;
    au.z = ((wA.z >> cl) & 0x10001u) * 0x3F80u;
    au.w = ((wA.w >> cl) & 0x10001u) * 0x3F80u;
    const bf16x8 av = __builtin_bit_cast(bf16x8, au);
    #pragma unroll
    for (int nt = 0; nt < 4; ++nt) {
        bf16x8 bv;
        bv[0] = (__bf16)buf[nt][0].x; bv[1] = (__bf16)buf[nt][0].y;
        bv[2] = (__bf16)buf[nt][0].z; bv[3] = (__bf16)buf[nt][0].w;
        bv[4] = (__bf16)buf[nt][1].x; bv[5] = (__bf16)buf[nt][1].y;
        bv[6] = (__bf16)buf[nt][1].z; bv[7] = (__bf16)buf[nt][1].w;
        f32x4& ac = (nt == 0) ? a0 : (nt == 1) ? a1 : (nt == 2) ? a2 : a3;
        ac = __builtin_amdgcn_mfma_f32_16x16x32_bf16(av, bv, ac, 0, 0, 0);
    }
}

// ---------------------------------------------------------------------------
// Fused per-chunk kernel. Block = 256 thr = 4 waves; owns one 256-pixel chunk
// of one (b, level).
// Phase B prefetch of ks=0 is issued FIRST (8 float4s in flight under phase A).
// Phase A: thread = pixel; 16-instance loop; sr = exact 2x2 scribble average
//   (bilinear, integer scale, half-pixel); threshold folded to s4 > 2; 16 mask
//   bits -> u16 LDS. cnt via wave ballot-popcount -> LDS atomic -> chunk slot.
//   Argmax key only when a whole wave sees zero foreground for an instance
//   (dead unless cnt==0 globally). key=(bits(sr)<<32)|(~pix).
// Phase B: ssum[i,c] = sum_p mask[i,p]*feat[c,p] via mfma_f32_16x16x32_bf16,
//   K = 256 chunk pixels = 8 k-steps, 2-buffer software pipeline (prefetch
//   ks+1 while computing ks): ~16 float4 loads in flight per wave.
//   A-frag: ((word>>i)&0x10001)*0x3F80 = two bf16 {0,1}. C/D (m89):
//   row=(lane>>4)*4+reg=instance, col=lane&15=channel. Wave w = channels
//   w*64..w*64+63. Partial [16][256] -> private chunk slot (no atomics).
// ---------------------------------------------------------------------------
template<int W, int S, int P>
__device__ __forceinline__ void do_chunk(const float* __restrict__ f,
                                         const float* __restrict__ scr,
                                         float* __restrict__ ssp,
                                         int* __restrict__ cntp,
                                         unsigned long long* __restrict__ keyp,
                                         int b, int chunk, int slot, int tid,
                                         uint16_t* __restrict__ lmask,
                                         int* __restrict__ lcnt,
                                         unsigned long long* __restrict__ lkey) {
    // ---- phase-B addressing + early prefetch of ks=0 ----
    const int wave = tid >> 6;
    const int lane = tid & 63;
    const int kg = lane >> 4;   // k-subgroup 0..3
    const int cl = lane & 15;   // channel-within-tile (B/D) AND instance row (A)
    const int c0 = wave * 64;
    const int kb = chunk * 256;
    const float* fp0 = f + ((size_t)b * NC + c0 + cl) * P + kb + kg * 8;
    float4 bA[4][2], bB[4][2];
    #pragma unroll
    for (int nt = 0; nt < 4; ++nt) {
        const float* fr = fp0 + (size_t)(nt * 16) * P;
        bA[nt][0] = ld4(fr);
        bA[nt][1] = ld4(fr + 4);
    }

    // ---- phase A ----
    const int pix = chunk * 256 + tid;
    const int y = pix / W;
    const int x = pix - y * W;
    const int r0 = S * y + (S / 2 - 1);
    const int c0s = S * x + (S / 2 - 1);
    const float* sb = scr + (size_t)b * NI * (SH * SH) + (size_t)r0 * SH;
    unsigned int mword = 0;
    #pragma unroll
    for (int i = 0; i < NI; ++i) {
        const float* sp = sb + (size_t)i * (SH * SH);
        float s4;
        if constexpr (S == 4) {
            // c0s-1 = 4x -> 16B-aligned float4; cols 4x+1, 4x+2 are .y/.z
            float4 q0 = ld4(sp + (c0s - 1));
            float4 q1 = ld4(sp + SH + (c0s - 1));
            s4 = (q0.y + q0.z) + (q1.y + q1.z);
        } else {
            s4 = (sp[c0s] + sp[c0s + 1]) + (sp[SH + c0s] + sp[SH + c0s + 1]);
        }
        bool bit = s4 > 2.0f;                 // == (0.25*s4 > 0.5)
        mword |= bit ? (1u << i) : 0u;
        unsigned long long bal = __ballot(bit);
        if (lane == 0) atomicAdd(&lcnt[i], (int)__popcll(bal));
        if (bal == 0ull) {                    // whole wave empty -> argmax path
            unsigned int srb = __float_as_uint(0.25f * s4);
            unsigned int mx = srb;
            #pragma unroll
            for (int off = 1; off < 64; off <<= 1) {
                unsigned int o = __shfl_xor(mx, off, 64);
                mx = (o > mx) ? o : mx;
            }
            unsigned long long win = __ballot(srb == mx);
            if (lane == 0) {
                int wl = __ffsll((unsigned long long)win) - 1;  // first = smallest pix
                unsigned int wpix = (unsigned int)(chunk * 256 + (tid & ~63) + wl);
                unsigned long long key = (((unsigned long long)mx) << 32)
                                       | (unsigned long long)(0xFFFFFFFFu - wpix);
                atomicMax(&lkey[i], key);
            }
        }
    }
    lmask[tid] = (uint16_t)mword;
    __syncthreads();
    if (tid < NI) {
        cntp[slot * NI + tid] = lcnt[tid];
        keyp[slot * NI + tid] = lkey[tid];
    }

    // ---- phase B: 2-buffer pipelined MFMA over 8 k-steps ----
    const uint16_t* lmp = lmask + kg * 8;
    f32x4 acc0 = {0.f, 0.f, 0.f, 0.f};
    f32x4 acc1 = {0.f, 0.f, 0.f, 0.f};
    f32x4 acc2 = {0.f, 0.f, 0.f, 0.f};
    f32x4 acc3 = {0.f, 0.f, 0.f, 0.f};
    #pragma unroll
    for (int ks = 0; ks < 8; ks += 2) {
        #pragma unroll
        for (int nt = 0; nt < 4; ++nt) {       // prefetch ks+1 -> bB
            const float* fr = fp0 + (size_t)(nt * 16) * P + (ks + 1) * 32;
            bB[nt][0] = ld4(fr);
            bB[nt][1] = ld4(fr + 4);
        }
        mfma_step(lmp, ks, cl, bA, acc0, acc1, acc2, acc3);
        if (ks + 2 < 8) {
            #pragma unroll
            for (int nt = 0; nt < 4; ++nt) {   // prefetch ks+2 -> bA
                const float* fr = fp0 + (size_t)(nt * 16) * P + (ks + 2) * 32;
                bA[nt][0] = ld4(fr);
                bA[nt][1] = ld4(fr + 4);
            }
        }
        mfma_step(lmp, ks + 1, cl, bB, acc0, acc1, acc2, acc3);
    }
    float* sb2 = ssp + (size_t)slot * (NI * NC);
    #pragma unroll
    for (int nt = 0; nt < 4; ++nt) {
        const f32x4 ac = (nt == 0) ? acc0 : (nt == 1) ? acc1 : (nt == 2) ? acc2 : acc3;
        const int c = c0 + nt * 16 + cl;
        #pragma unroll
        for (int r = 0; r < 4; ++r)
            sb2[(kg * 4 + r) * NC + c] = ac[r];
    }
}

__global__ __launch_bounds__(256, 2) void fused_kernel(const float* __restrict__ f0,
                                                       const float* __restrict__ f1,
                                                       const float* __restrict__ f2,
                                                       const float* __restrict__ scr,
                                                       float* __restrict__ ssp,
                                                       int* __restrict__ cntp,
                                                       unsigned long long* __restrict__ keyp) {
    __shared__ __align__(16) uint16_t lmask[256];
    __shared__ int lcnt[NI];
    __shared__ unsigned long long lkey[NI];
    const int tid = threadIdx.x;
    const int b = blockIdx.y;
    const int bx = blockIdx.x;
    if (tid < NI) { lcnt[tid] = 0; lkey[tid] = 0ull; }
    __syncthreads();
    const int slot = b * NCH + bx;
    if (bx < 64) {
        do_chunk<128, 4, 16384>(f0, scr, ssp, cntp, keyp, b, bx, slot, tid,
                                lmask, lcnt, lkey);
    } else if (bx < 80) {
        do_chunk<64, 8, 4096>(f1, scr, ssp, cntp, keyp, b, bx - 64, slot, tid,
                              lmask, lcnt, lkey);
    } else {
        do_chunk<32, 16, 1024>(f2, scr, ssp, cntp, keyp, b, bx - 80, slot, tid,
                               lmask, lcnt, lkey);
    }
}

// ---------------------------------------------------------------------------
// Finalize: grid (128, 4). Block = (b,i) x 64-channel quarter. 4 j-groups sum
// the per-chunk partials in parallel, LDS reduce; cnt/key reduced via LDS
// atomics. out = mean over levels of (cnt>0 ? ssum/cnt : feat[argmax]).
// ---------------------------------------------------------------------------
__global__ __launch_bounds__(256) void final_kernel(const float* __restrict__ f0,
                                                    const float* __restrict__ f1,
                                                    const float* __restrict__ f2,
                                                    const int* __restrict__ cntp,
                                                    const unsigned long long* __restrict__ keyp,
                                                    const float* __restrict__ ssp,
                                                    float* __restrict__ out) {
    __shared__ int scnt[3];
    __shared__ unsigned long long skey[3];
    __shared__ float red[4][64];
    const int bi = blockIdx.x;       // b*NI + i
    const int cq = blockIdx.y;       // channel quarter
    const int b = bi >> 4;
    const int i = bi & 15;
    const int tid = threadIdx.x;
    const int cl = tid & 63;
    const int jg = tid >> 6;
    const int CH[3] = {64, 16, 4};
    const int O[3] = {0, 64, 80};
    if (tid < 3) { scnt[tid] = 0; skey[tid] = 0ull; }
    __syncthreads();
    if (tid < NCH) {
        int l = (tid < 64) ? 0 : (tid < 80) ? 1 : 2;
        const int slot = b * NCH + tid;    // tid == O[l] + j already
        atomicAdd(&scnt[l], cntp[slot * NI + i]);
        atomicMax(&skey[l], keyp[slot * NI + i]);
    }
    __syncthreads();
    const float* fl[3] = {f0, f1, f2};
    const int Ps[3] = {16384, 4096, 1024};
    float r = 0.f;
    #pragma unroll
    for (int l = 0; l < 3; ++l) {
        const int cn = scnt[l];          // block-uniform
        if (cn > 0) {
            float s = 0.f;
            for (int j = jg; j < CH[l]; j += 4)
                s += ssp[((size_t)(b * NCH + O[l] + j) * NI + i) * NC + cq * 64 + cl];
            red[jg][cl] = s;
            __syncthreads();
            if (jg == 0)
                r += ((red[0][cl] + red[1][cl]) + (red[2][cl] + red[3][cl])) / (float)cn;
            __syncthreads();
        } else if (jg == 0) {
            unsigned int p = 0xFFFFFFFFu - (unsigned int)(skey[l] & 0xFFFFFFFFull);
            r += fl[l][((size_t)b * NC + cq * 64 + cl) * Ps[l] + p];
        }
    }
    if (jg == 0) out[(size_t)bi * NC + cq * 64 + cl] = r * (1.f / 3.f);
}

extern "C" void kernel_launch(void* const* d_in, const int* in_sizes, int n_in,
                              void* d_out, int out_size, void* d_ws, size_t ws_size,
                              hipStream_t stream) {
    const float* f0  = (const float*)d_in[0];   // [8,256,128,128]
    const float* f1  = (const float*)d_in[1];   // [8,256,64,64]
    const float* f2  = (const float*)d_in[2];   // [8,256,32,32]
    const float* scr = (const float*)d_in[3];   // [8,16,512,512]
    float* out = (float*)d_out;                 // [8,16,256]
    char* ws = (char*)d_ws;
    if (ws_size < WS_NEED) return;  // visible failure rather than corruption

    float* ssp = (float*)(ws + OFF_SSP);
    int* cntp = (int*)(ws + OFF_CNT);
    unsigned long long* keyp = (unsigned long long*)(ws + OFF_KEY);

    // no memset: every ws slot below is written unconditionally each call
    fused_kernel<<<dim3(NCH, NB), 256, 0, stream>>>(f0, f1, f2, scr, ssp, cntp, keyp);
    final_kernel<<<dim3(NB * NI, 4), 256, 0, stream>>>(f0, f1, f2, cntp, keyp, ssp, out);
}

// Round 7
// 63.718 us; speedup vs baseline: 1.1836x; 1.0925x over previous
//
#include <hip/hip_runtime.h>
#include <stdint.h>

#define NB 8
#define NI 16
#define NC 256
#define SH 512
#define NCH 84   // 256-pixel chunks per batch: 64 (L0) + 16 (L1) + 4 (L2)

typedef __bf16 bf16x8 __attribute__((ext_vector_type(8)));
typedef float f32x4 __attribute__((ext_vector_type(4)));
typedef uint32_t u32x4 __attribute__((ext_vector_type(4)));

// ws layout (bytes) — every slot written unconditionally every call: NO memset.
static const size_t OFF_SSP = 0;                                         // f32 [NB][NCH][NI][NC]
static const size_t OFF_CNT = OFF_SSP + (size_t)NB * NCH * NI * NC * 4;  // int [NB][NCH][NI]
static const size_t OFF_KEY = OFF_CNT + (size_t)NB * NCH * NI * 4;       // u64 [NB][NCH][NI]
static const size_t WS_NEED = OFF_KEY + (size_t)NB * NCH * NI * 8;       // ~11.1 MB

__device__ __forceinline__ float4 ld4(const float* p) {
    return *reinterpret_cast<const float4*>(p);
}

// One MFMA k-step for this wave's 2 n-tiles: A-frag from mask words,
// B-frag packed from prefetched float4s (RNE v_cvt_pk_bf16_f32 via __bf16).
__device__ __forceinline__ void mfma_step(const uint16_t* __restrict__ lmp, int ks, int cl,
                                          const float4 (&buf)[2][2],
                                          f32x4& a0, f32x4& a1) {
    const uint4 wA = *reinterpret_cast<const uint4*>(lmp + ks * 32);
    u32x4 au;
    au.x = ((wA.x >> cl) & 0x10001u) * 0x3F80u;
    au.y = ((wA.y >> cl) & 0x10001u) * 0x3F80u;
    au.z = ((wA.z >> cl) & 0x10001u) * 0x3F80u;
    au.w = ((wA.w >> cl) & 0x10001u) * 0x3F80u;
    const bf16x8 av = __builtin_bit_cast(bf16x8, au);
    #pragma unroll
    for (int nt = 0; nt < 2; ++nt) {
        bf16x8 bv;
        bv[0] = (__bf16)buf[nt][0].x; bv[1] = (__bf16)buf[nt][0].y;
        bv[2] = (__bf16)buf[nt][0].z; bv[3] = (__bf16)buf[nt][0].w;
        bv[4] = (__bf16)buf[nt][1].x; bv[5] = (__bf16)buf[nt][1].y;
        bv[6] = (__bf16)buf[nt][1].z; bv[7] = (__bf16)buf[nt][1].w;
        f32x4& ac = (nt == 0) ? a0 : a1;
        ac = __builtin_amdgcn_mfma_f32_16x16x32_bf16(av, bv, ac, 0, 0, 0);
    }
}

// ---------------------------------------------------------------------------
// Fused per-chunk kernel. Block = 512 thr = 8 waves; owns one 256-pixel chunk
// of one (b, level). 672-block grid -> ~21 waves/CU (vs 7 at 256 thr).
// Phase A (instance-split): tid<256 -> pixel tid, instances 0..7; tid>=256 ->
//   pixel tid-256, instances 8..15. 8-deep ballot chain (was 16), 16 scattered
//   loads/thread (was 32). sr = exact 2x2 scribble average (bilinear, integer
//   scale, half-pixel); threshold folded to s4 > 2. u8 halves merged to u16 in
//   LDS. cnt via wave ballot-popcount -> LDS atomic -> chunk slot. Argmax key
//   only when a whole wave sees zero foreground (dead unless cnt==0 globally);
//   key=(bits(sr)<<32)|(~pix) -> max = max sr, first index.
// Phase B: ssum[i,c] = sum_p mask[i,p]*feat[c,p] via mfma_f32_16x16x32_bf16.
//   Wave w = channels w*32..w*32+31 (2 n-tiles); K = 256 chunk pixels =
//   8 k-steps, 2-buffer pipeline. A-frag: ((word>>i)&0x10001)*0x3F80 = two
//   bf16 {0,1}. C/D (m89): row=(lane>>4)*4+reg=instance, col=lane&15=channel.
//   Partial [16][256] -> private chunk slot (no atomics, no zeroing).
// ---------------------------------------------------------------------------
template<int W, int S, int P>
__device__ __forceinline__ void do_chunk(const float* __restrict__ f,
                                         const float* __restrict__ scr,
                                         float* __restrict__ ssp,
                                         int* __restrict__ cntp,
                                         unsigned long long* __restrict__ keyp,
                                         int b, int chunk, int slot, int tid,
                                         uint8_t* __restrict__ lmask8,
                                         uint16_t* __restrict__ lmask16,
                                         int* __restrict__ lcnt,
                                         unsigned long long* __restrict__ lkey) {
    // ---- phase-B addressing + early prefetch of ks=0 ----
    const int wave = tid >> 6;
    const int lane = tid & 63;
    const int kg = lane >> 4;   // k-subgroup 0..3
    const int cl = lane & 15;   // channel-within-tile (B/D) AND instance row (A)
    const int c0 = wave * 32;
    const int kb = chunk * 256;
    const float* fp0 = f + ((size_t)b * NC + c0 + cl) * P + kb + kg * 8;
    float4 bA[2][2], bB[2][2];
    #pragma unroll
    for (int nt = 0; nt < 2; ++nt) {
        const float* fr = fp0 + (size_t)(nt * 16) * P;
        bA[nt][0] = ld4(fr);
        bA[nt][1] = ld4(fr + 4);
    }

    // ---- phase A ----
    const int gi = tid >> 8;        // instance group: 0 -> 0..7, 1 -> 8..15
    const int p = tid & 255;        // pixel within chunk
    const int pix = chunk * 256 + p;
    const int y = pix / W;
    const int x = pix - y * W;
    const int r0 = S * y + (S / 2 - 1);
    const int c0s = S * x + (S / 2 - 1);
    const float* sb = scr + ((size_t)b * NI + gi * 8) * (SH * SH) + (size_t)r0 * SH;
    unsigned int mword = 0;
    #pragma unroll
    for (int i = 0; i < 8; ++i) {
        const float* sp = sb + (size_t)i * (SH * SH);
        float s4;
        if constexpr (S == 4) {
            // c0s-1 = 4x -> 16B-aligned float4; cols 4x+1, 4x+2 are .y/.z
            float4 q0 = ld4(sp + (c0s - 1));
            float4 q1 = ld4(sp + SH + (c0s - 1));
            s4 = (q0.y + q0.z) + (q1.y + q1.z);
        } else {
            s4 = (sp[c0s] + sp[c0s + 1]) + (sp[SH + c0s] + sp[SH + c0s + 1]);
        }
        bool bit = s4 > 2.0f;                 // == (0.25*s4 > 0.5)
        mword |= bit ? (1u << i) : 0u;
        unsigned long long bal = __ballot(bit);
        if (lane == 0) atomicAdd(&lcnt[gi * 8 + i], (int)__popcll(bal));
        if (bal == 0ull) {                    // whole wave empty -> argmax path
            unsigned int srb = __float_as_uint(0.25f * s4);
            unsigned int mx = srb;
            #pragma unroll
            for (int off = 1; off < 64; off <<= 1) {
                unsigned int o = __shfl_xor(mx, off, 64);
                mx = (o > mx) ? o : mx;
            }
            unsigned long long win = __ballot(srb == mx);
            if (lane == 0) {
                int wl = __ffsll((unsigned long long)win) - 1;  // first = smallest pix
                unsigned int wpix = (unsigned int)(chunk * 256 + (p & ~63) + wl);
                unsigned long long key = (((unsigned long long)mx) << 32)
                                       | (unsigned long long)(0xFFFFFFFFu - wpix);
                atomicMax(&lkey[gi * 8 + i], key);
            }
        }
    }
    lmask8[gi * 256 + p] = (uint8_t)mword;
    __syncthreads();
    if (tid < 256)
        lmask16[tid] = (uint16_t)(lmask8[tid] | ((unsigned)lmask8[256 + tid] << 8));
    if (tid < NI) {
        cntp[slot * NI + tid] = lcnt[tid];
        keyp[slot * NI + tid] = lkey[tid];
    }
    __syncthreads();

    // ---- phase B: 2-buffer pipelined MFMA over 8 k-steps ----
    const uint16_t* lmp = lmask16 + kg * 8;
    f32x4 acc0 = {0.f, 0.f, 0.f, 0.f};
    f32x4 acc1 = {0.f, 0.f, 0.f, 0.f};
    #pragma unroll
    for (int ks = 0; ks < 8; ks += 2) {
        #pragma unroll
        for (int nt = 0; nt < 2; ++nt) {       // prefetch ks+1 -> bB
            const float* fr = fp0 + (size_t)(nt * 16) * P + (ks + 1) * 32;
            bB[nt][0] = ld4(fr);
            bB[nt][1] = ld4(fr + 4);
        }
        mfma_step(lmp, ks, cl, bA, acc0, acc1);
        if (ks + 2 < 8) {
            #pragma unroll
            for (int nt = 0; nt < 2; ++nt) {   // prefetch ks+2 -> bA
                const float* fr = fp0 + (size_t)(nt * 16) * P + (ks + 2) * 32;
                bA[nt][0] = ld4(fr);
                bA[nt][1] = ld4(fr + 4);
            }
        }
        mfma_step(lmp, ks + 1, cl, bB, acc0, acc1);
    }
    float* sb2 = ssp + (size_t)slot * (NI * NC);
    #pragma unroll
    for (int nt = 0; nt < 2; ++nt) {
        const f32x4 ac = (nt == 0) ? acc0 : acc1;
        const int c = c0 + nt * 16 + cl;
        #pragma unroll
        for (int r = 0; r < 4; ++r)
            sb2[(kg * 4 + r) * NC + c] = ac[r];
    }
}

__global__ __launch_bounds__(512) void fused_kernel(const float* __restrict__ f0,
                                                    const float* __restrict__ f1,
                                                    const float* __restrict__ f2,
                                                    const float* __restrict__ scr,
                                                    float* __restrict__ ssp,
                                                    int* __restrict__ cntp,
                                                    unsigned long long* __restrict__ keyp) {
    __shared__ uint8_t lmask8[512];
    __shared__ __align__(16) uint16_t lmask16[256];
    __shared__ int lcnt[NI];
    __shared__ unsigned long long lkey[NI];
    const int tid = threadIdx.x;
    const int b = blockIdx.y;
    const int bx = blockIdx.x;
    if (tid < NI) { lcnt[tid] = 0; lkey[tid] = 0ull; }
    __syncthreads();
    const int slot = b * NCH + bx;
    if (bx < 64) {
        do_chunk<128, 4, 16384>(f0, scr, ssp, cntp, keyp, b, bx, slot, tid,
                                lmask8, lmask16, lcnt, lkey);
    } else if (bx < 80) {
        do_chunk<64, 8, 4096>(f1, scr, ssp, cntp, keyp, b, bx - 64, slot, tid,
                              lmask8, lmask16, lcnt, lkey);
    } else {
        do_chunk<32, 16, 1024>(f2, scr, ssp, cntp, keyp, b, bx - 80, slot, tid,
                               lmask8, lmask16, lcnt, lkey);
    }
}

// ---------------------------------------------------------------------------
// Finalize: grid (128, 4). Block = (b,i) x 64-channel quarter. 4 j-groups sum
// the per-chunk partials in parallel, LDS reduce; cnt/key reduced via LDS
// atomics. out = mean over levels of (cnt>0 ? ssum/cnt : feat[argmax]).
// ---------------------------------------------------------------------------
__global__ __launch_bounds__(256) void final_kernel(const float* __restrict__ f0,
                                                    const float* __restrict__ f1,
                                                    const float* __restrict__ f2,
                                                    const int* __restrict__ cntp,
                                                    const unsigned long long* __restrict__ keyp,
                                                    const float* __restrict__ ssp,
                                                    float* __restrict__ out) {
    __shared__ int scnt[3];
    __shared__ unsigned long long skey[3];
    __shared__ float red[4][64];
    const int bi = blockIdx.x;       // b*NI + i
    const int cq = blockIdx.y;       // channel quarter
    const int b = bi >> 4;
    const int i = bi & 15;
    const int tid = threadIdx.x;
    const int cl = tid & 63;
    const int jg = tid >> 6;
    const int CH[3] = {64, 16, 4};
    const int O[3] = {0, 64, 80};
    if (tid < 3) { scnt[tid] = 0; skey[tid] = 0ull; }
    __syncthreads();
    if (tid < NCH) {
        int l = (tid < 64) ? 0 : (tid < 80) ? 1 : 2;
        const int slot = b * NCH + tid;    // tid == O[l] + j already
        atomicAdd(&scnt[l], cntp[slot * NI + i]);
        atomicMax(&skey[l], keyp[slot * NI + i]);
    }
    __syncthreads();
    const float* fl[3] = {f0, f1, f2};
    const int Ps[3] = {16384, 4096, 1024};
    float r = 0.f;
    #pragma unroll
    for (int l = 0; l < 3; ++l) {
        const int cn = scnt[l];          // block-uniform
        if (cn > 0) {
            float s = 0.f;
            for (int j = jg; j < CH[l]; j += 4)
                s += ssp[((size_t)(b * NCH + O[l] + j) * NI + i) * NC + cq * 64 + cl];
            red[jg][cl] = s;
            __syncthreads();
            if (jg == 0)
                r += ((red[0][cl] + red[1][cl]) + (red[2][cl] + red[3][cl])) / (float)cn;
            __syncthreads();
        } else if (jg == 0) {
            unsigned int p = 0xFFFFFFFFu - (unsigned int)(skey[l] & 0xFFFFFFFFull);
            r += fl[l][((size_t)b * NC + cq * 64 + cl) * Ps[l] + p];
        }
    }
    if (jg == 0) out[(size_t)bi * NC + cq * 64 + cl] = r * (1.f / 3.f);
}

extern "C" void kernel_launch(void* const* d_in, const int* in_sizes, int n_in,
                              void* d_out, int out_size, void* d_ws, size_t ws_size,
                              hipStream_t stream) {
    const float* f0  = (const float*)d_in[0];   // [8,256,128,128]
    const float* f1  = (const float*)d_in[1];   // [8,256,64,64]
    const float* f2  = (const float*)d_in[2];   // [8,256,32,32]
    const float* scr = (const float*)d_in[3];   // [8,16,512,512]
    float* out = (float*)d_out;                 // [8,16,256]
    char* ws = (char*)d_ws;
    if (ws_size < WS_NEED) return;  // visible failure rather than corruption

    float* ssp = (float*)(ws + OFF_SSP);
    int* cntp = (int*)(ws + OFF_CNT);
    unsigned long long* keyp = (unsigned long long*)(ws + OFF_KEY);

    // no memset: every ws slot below is written unconditionally each call
    fused_kernel<<<dim3(NCH, NB), 512, 0, stream>>>(f0, f1, f2, scr, ssp, cntp, keyp);
    final_kernel<<<dim3(NB * NI, 4), 256, 0, stream>>>(f0, f1, f2, cntp, keyp, ssp, out);
}